// Round 6
// baseline (663.431 us; speedup 1.0000x reference)
//
#include <hip/hip_runtime.h>
#include <hip/hip_bf16.h>

#define IN_F 4096
#define OUT_F 4096
#define M_TOK 8192
#define RANK 16

typedef __attribute__((ext_vector_type(4))) float f32x4;
typedef __attribute__((ext_vector_type(8))) short short8;

struct alignas(16) bf16x8_s { __hip_bfloat16 v[8]; };

// ---------------------------------------------------------------------------
// Kernel 1 (was 1b): dequant int4 codes -> bf16 with rank-16 LoRA folded in.
// DELIBERATELY UNCHANGED (attribution round: conv is deleted; if total drops
// ~140us conv was real kernel time and deq gets rebuilt next round with that
// knowledge; if total barely moves, the ~280us prep residual was phantom).
//   W[o][i] = bf16( scales[o][i/64]*(q-8) + 2*sum_r A[i][r]*B[r][o] )
// ---------------------------------------------------------------------------
#define DEQ_BLOCKS 2048

__global__ __launch_bounds__(256) void deq_kernel(
    const int* __restrict__ q,
    const float* __restrict__ scales,
    const float* __restrict__ lA,   // [IN_F][RANK]
    const float* __restrict__ lB,   // [RANK][OUT_F]
    __hip_bfloat16* __restrict__ W) {
    const int tid = threadIdx.x;
    const int bid = blockIdx.x;                  // 0..2047
    const int o0 = (bid >> 1) * 4;               // block-uniform
    const int i0 = (bid & 1) * 2048 + tid * 8;

    float bw[16][4];
#pragma unroll
    for (int r = 0; r < 16; ++r)
#pragma unroll
        for (int oi = 0; oi < 4; ++oi)
            bw[r][oi] = 2.0f * lB[(size_t)r * OUT_F + o0 + oi];

    float fold[4][8];
#pragma unroll
    for (int e = 0; e < 8; ++e) {
        const float* ar = lA + (size_t)(i0 + e) * RANK;
        float4 a0 = *(const float4*)(ar + 0);
        float4 a1 = *(const float4*)(ar + 4);
        float4 a2 = *(const float4*)(ar + 8);
        float4 a3 = *(const float4*)(ar + 12);
#pragma unroll
        for (int oi = 0; oi < 4; ++oi) {
            float f = a0.x * bw[0][oi] + a0.y * bw[1][oi]
                    + a0.z * bw[2][oi] + a0.w * bw[3][oi]
                    + a1.x * bw[4][oi] + a1.y * bw[5][oi]
                    + a1.z * bw[6][oi] + a1.w * bw[7][oi]
                    + a2.x * bw[8][oi] + a2.y * bw[9][oi]
                    + a2.z * bw[10][oi] + a2.w * bw[11][oi]
                    + a3.x * bw[12][oi] + a3.y * bw[13][oi]
                    + a3.z * bw[14][oi] + a3.w * bw[15][oi];
            fold[oi][e] = f;
        }
    }

#pragma unroll
    for (int oi = 0; oi < 4; ++oi) {
        const int o = o0 + oi;
        const float s = scales[o * 64 + (i0 >> 6)];
        const int4* qp = (const int4*)(q + (size_t)o * IN_F + i0);
        int4 q0 = qp[0];
        int4 q1 = qp[1];
        bf16x8_s r;
        r.v[0] = __float2bfloat16(s * (float)(q0.x - 8) + fold[oi][0]);
        r.v[1] = __float2bfloat16(s * (float)(q0.y - 8) + fold[oi][1]);
        r.v[2] = __float2bfloat16(s * (float)(q0.z - 8) + fold[oi][2]);
        r.v[3] = __float2bfloat16(s * (float)(q0.w - 8) + fold[oi][3]);
        r.v[4] = __float2bfloat16(s * (float)(q1.x - 8) + fold[oi][4]);
        r.v[5] = __float2bfloat16(s * (float)(q1.y - 8) + fold[oi][5]);
        r.v[6] = __float2bfloat16(s * (float)(q1.z - 8) + fold[oi][6]);
        r.v[7] = __float2bfloat16(s * (float)(q1.w - 8) + fold[oi][7]);
        *(bf16x8_s*)(W + (size_t)o * IN_F + i0) = r;
    }
}

// ---------------------------------------------------------------------------
// Kernel 2: 256x256 GEMM, R6: conv FUSED into A-staging.
// A is now reg-staged directly from fp32 x (conv_kernel deleted):
//   p0 issues 8 float4 loads (tile t+1's A, linear global addresses),
//   p2/p3 convert + ds_write_b128 to the SWIZZLED LDS slot (reg-staging
//   allows write-side swizzle; fragment-read map identical to R5).
// B staging unchanged (global_load_lds, granule-swizzled source).
// New sync ledger per K-tile t:
//   p0: rd A(h0,k0)+B(k0); issue 8 float4 (A of t+1)
//   p1: rd A(h1,k0);       stage Y.B1(t+1)  [2 glds]
//   p2: rd A(h0,k1)+B(k1); cvt+ds_write Y.A0 (compiler vmcnt-waits floats)
//   p3: rd A(h1,k1);       stage X.B0(t+2) [2 glds]; cvt+ds_write Y.A1;
//       lgkmcnt(0)  <- fences the two A ds_writes before next tile's readers
//       vmcnt(2)    <- drains p1's B1 (t+1 data); keeps p3's 2 (t+2) in flight
// Region race audit: Y.A0 written p2(t), last read p2(t-1) [4 barriers
// earlier]; Y.A1 written p3(t), last read p3(t-1); X.B0 staged p3(t), last
// read p2(t) by wn0/1 whose reads are consumed before their p3-top barrier.
// Float-load latency (~900cy HBM) is covered by p0->p2 (2 MFMA phases).
// ---------------------------------------------------------------------------
#define BK 64
#define NT (IN_F / BK)   // 64 K-tiles

__device__ __forceinline__ short8 ldfrag(const short* p, int half, int row, int gran) {
    // swizzled read: LDS granule slot (gran ^ (row&7)) holds global granule gran
    return *(const short8*)(p + half * 8192 + row * 64 + ((gran ^ (row & 7)) * 8));
}

// B half-tile stage via global_load_lds (unchanged from R5): linear LDS dest,
// st-swizzle applied by permuting the GLOBAL source granule.
#define STAGE_B(LDSbuf, ROW0, K0)                                             \
    {                                                                         \
        _Pragma("unroll")                                                     \
        for (int j = 0; j < 2; ++j) {                                         \
            const __hip_bfloat16* g = Wq +                                    \
                (size_t)((ROW0) + j * 64 + wave * 8 + srow) * IN_F + (K0) + sgc; \
            __builtin_amdgcn_global_load_lds(                                 \
                (const __attribute__((address_space(1))) void*)g,             \
                (__attribute__((address_space(3))) void*)((LDSbuf) + (j * 64 + wave * 8) * 64), \
                16, 0, 0);                                                    \
        }                                                                     \
    }

// A: issue 8 float4 loads for one K-tile (2 halves x 2 j x [f4,f4]) from x.
// Linear source: granule gc = lane&7 of row (wave*8+srow); cols K0+gc*8.
#define LOAD_A_F32(K0)                                                        \
    {                                                                         \
        _Pragma("unroll")                                                     \
        for (int h = 0; h < 2; ++h)                                           \
        _Pragma("unroll")                                                     \
        for (int j = 0; j < 2; ++j) {                                         \
            const float* gp = xf +                                            \
                (size_t)(m0 + h * 128 + j * 64 + wave * 8 + srow) * IN_F +    \
                (K0) + (lane & 7) * 8;                                        \
            axf[h * 2 + j][0] = *(const float4*)gp;                           \
            axf[h * 2 + j][1] = *(const float4*)(gp + 4);                     \
        }                                                                     \
    }

// convert + write one A half-tile into LDS at the swizzled slot.
#define WRITE_A(DSTBUF, H)                                                    \
    {                                                                         \
        _Pragma("unroll")                                                     \
        for (int j = 0; j < 2; ++j) {                                         \
            bf16x8_s pk;                                                      \
            const float4 u0 = axf[(H) * 2 + j][0];                            \
            const float4 u1 = axf[(H) * 2 + j][1];                            \
            pk.v[0] = __float2bfloat16(u0.x); pk.v[1] = __float2bfloat16(u0.y); \
            pk.v[2] = __float2bfloat16(u0.z); pk.v[3] = __float2bfloat16(u0.w); \
            pk.v[4] = __float2bfloat16(u1.x); pk.v[5] = __float2bfloat16(u1.y); \
            pk.v[6] = __float2bfloat16(u1.z); pk.v[7] = __float2bfloat16(u1.w); \
            __hip_bfloat16* dst = (DSTBUF) + (H) * 8192 +                     \
                (j * 64 + wave * 8 + srow) * 64 + ((lane & 7) ^ srow) * 8;    \
            *(bf16x8_s*)dst = pk;                                             \
        }                                                                     \
    }

#define RD_A(BUF, HALF, KG)                                                   \
    _Pragma("unroll") for (int f = 0; f < 4; ++f)                             \
        fa[f] = ldfrag(BUF, HALF, wm * 64 + f * 16 + fr, (KG) * 4 + fc);

#define RD_B(BUF, KG)                                                         \
    _Pragma("unroll") for (int g2 = 0; g2 < 4; ++g2)                          \
        fb[g2] = ldfrag(BUF, bhalf, brow0 + g2 * 16 + fr, (KG) * 4 + fc);

#define MFMA16(MH)                                                            \
    _Pragma("unroll") for (int f = 0; f < 4; ++f)                             \
    _Pragma("unroll") for (int g2 = 0; g2 < 4; ++g2)                          \
        acc[(MH) * 4 + f][g2] = __builtin_amdgcn_mfma_f32_16x16x32_bf16(      \
            fa[f], fb[g2], acc[(MH) * 4 + f][g2], 0, 0, 0);

#define BAR __builtin_amdgcn_s_barrier();

__global__ __launch_bounds__(512, 2) void qlora_gemm_kernel(
    const float* __restrict__ xf,            // [4096][IN_F] fp32 half-panel
    const __hip_bfloat16* __restrict__ Wq,   // [OUT_F][IN_F]  (B^T layout)
    const float* __restrict__ bias,          // [OUT_F]
    float* __restrict__ out) {               // [4096][OUT_F] fp32 half-panel
    __shared__ __hip_bfloat16 As[2][16384];  // [dbuf][half(2) x 128 x 64] = 64 KB
    __shared__ __hip_bfloat16 Bs[2][16384];  // 64 KB

    const int tid  = threadIdx.x;
    const int wave = tid >> 6;
    const int lane = tid & 63;
    const int wm = wave >> 2;                // 0..1  (M half of wave grid)
    const int wn = wave & 3;                 // 0..3  (N quarter: 64 cols each)

    // T1: bijective XCD swizzle (nwg=256, 256%8==0)
    const int wg = ((int)blockIdx.x & 7) * 32 + ((int)blockIdx.x >> 3);
    const int bx = wg & 15;                  // 16 N-tiles
    const int by = wg >> 4;                  // 16 M-tiles (half panel)
    const int m0 = by * 256;
    const int n0 = bx * 256;

    f32x4 acc[8][4];
#pragma unroll
    for (int i = 0; i < 8; ++i)
#pragma unroll
        for (int j = 0; j < 4; ++j)
            acc[i][j] = (f32x4){0.f, 0.f, 0.f, 0.f};

    // staging lane geometry: LDS slot p of row r holds global granule (p^(r&7))
    const int srow = lane >> 3;
    const int sgc  = ((lane & 7) ^ srow) * 8;

    // fragment read geometry (16x16x32): row = lane&15, k-granule = lane>>4
    const int fr = lane & 15;
    const int fc = lane >> 4;

    // wave's B slice: contiguous 64 cols = n0 + wn*64; in LDS halves of 128:
    const int bhalf = wn >> 1;
    const int brow0 = (wn & 1) * 64;

    const short* A0p = (const short*)As[0];
    const short* A1p = (const short*)As[1];
    const short* B0p = (const short*)Bs[0];
    const short* B1p = (const short*)Bs[1];

    short8 fa[4];
    short8 fb[4];
    float4 axf[4][2];   // in-flight A fp32: [half*2+j][lo/hi]

    // prologue: A(t0) via regs; B(t0) h0+h1 staged; B(t1) h0 staged (2 in
    // flight at loop entry, matching steady state p3's ledger).
    LOAD_A_F32(0);                            // t0 A (8 float4)
    STAGE_B(Bs[0],        n0,       0);       // t0 B h0
    STAGE_B(Bs[0] + 8192, n0 + 128, 0);       // t0 B h1
    STAGE_B(Bs[1],        n0,       BK);      // t1 B h0
    WRITE_A(As[0], 0);                        // compiler waits the floats
    WRITE_A(As[0], 1);
    asm volatile("s_waitcnt lgkmcnt(0)" ::: "memory");  // A writes visible
    asm volatile("s_waitcnt vmcnt(2)" ::: "memory");    // t0 B landed

    for (int it = 0; it < NT / 2; ++it) {
        const int t = it * 2;
        const int k_t1 = (t + 1) * BK;               // always in-bounds
        const int k_t2 = ((t + 2) & (NT - 1)) * BK;  // wraps: garbage tail
        const int k_t3 = ((t + 3) & (NT - 1)) * BK;  //  prefetch, in-bounds

        // ---- tile t (X=buf0, Y=buf1)
        BAR RD_A(A0p, 0, 0) RD_B(B0p, 0)
            LOAD_A_F32(k_t1)                         // A of t+1 -> regs
            MFMA16(0)
        BAR RD_A(A0p, 1, 0)
            STAGE_B(Bs[1] + 8192, n0 + 128, k_t1)    // Y.B1 (t+1)
            MFMA16(1)
        BAR RD_A(A0p, 0, 1) RD_B(B0p, 1)
            WRITE_A((__hip_bfloat16*)As[1], 0)       // Y.A0 (t+1)
            MFMA16(0)
        BAR RD_A(A0p, 1, 1)
            STAGE_B(Bs[0], n0, k_t2)                 // X.B0 (t+2)
            WRITE_A((__hip_bfloat16*)As[1], 1)       // Y.A1 (t+1)
            MFMA16(1)
        asm volatile("s_waitcnt lgkmcnt(0)" ::: "memory");  // A writes done
        asm volatile("s_waitcnt vmcnt(2)" ::: "memory");    // t+1 B landed

        // ---- tile t+1 (X=buf1, Y=buf0)
        BAR RD_A(A1p, 0, 0) RD_B(B1p, 0)
            LOAD_A_F32(k_t2)                         // A of t+2 -> regs
            MFMA16(0)
        BAR RD_A(A1p, 1, 0)
            STAGE_B(Bs[0] + 8192, n0 + 128, k_t2)    // Y.B1 (t+2)
            MFMA16(1)
        BAR RD_A(A1p, 0, 1) RD_B(B1p, 1)
            WRITE_A((__hip_bfloat16*)As[0], 0)       // Y.A0 (t+2)
            MFMA16(0)
        BAR RD_A(A1p, 1, 1)
            STAGE_B(Bs[1], n0, k_t3)                 // X.B0 (t+3)
            WRITE_A((__hip_bfloat16*)As[0], 1)       // Y.A1 (t+2)
            MFMA16(1)
        asm volatile("s_waitcnt lgkmcnt(0)" ::: "memory");  // A writes done
        asm volatile("s_waitcnt vmcnt(2)" ::: "memory");    // t+2 B landed
    }

    // drain leftover (garbage) prefetches before LDS deallocation at endpgm
    asm volatile("s_waitcnt vmcnt(0)" ::: "memory");

    // ---- epilogue: bias + store
    // C/D 16x16: col = lane&15, row = (lane>>4)*4 + reg  (m89-verified)
    const int cc  = lane & 15;
    const int rr4 = (lane >> 4) * 4;
    float bv[4];
#pragma unroll
    for (int g2 = 0; g2 < 4; ++g2)
        bv[g2] = bias[n0 + wn * 64 + g2 * 16 + cc];

#pragma unroll
    for (int mh = 0; mh < 2; ++mh)
#pragma unroll
        for (int f = 0; f < 4; ++f) {
            const int m = m0 + mh * 128 + wm * 64 + f * 16 + rr4;
#pragma unroll
            for (int g2 = 0; g2 < 4; ++g2) {
                const int n = n0 + wn * 64 + g2 * 16 + cc;
                float* op = out + (size_t)m * OUT_F + n;
                const f32x4 a = acc[mh * 4 + f][g2];
#pragma unroll
                for (int r = 0; r < 4; ++r)
                    op[(size_t)r * OUT_F] = a[r] + bv[g2];
            }
        }
}

// ---------------------------------------------------------------------------
extern "C" void kernel_launch(void* const* d_in, const int* in_sizes, int n_in,
                              void* d_out, int out_size, void* d_ws, size_t ws_size,
                              hipStream_t stream) {
    const float* x      = (const float*)d_in[0];   // [8,1024,4096] fp32
    const int*   qw     = (const int*)  d_in[1];   // [4096,4096] int32 codes
    const float* scales = (const float*)d_in[2];   // [4096,64] fp32
    const float* bias   = (const float*)d_in[3];   // [4096] fp32
    const float* lA     = (const float*)d_in[4];   // [4096,16] fp32
    const float* lB     = (const float*)d_in[5];   // [16,4096] fp32
    float* out = (float*)d_out;                    // [8,1024,4096] fp32

    // workspace: Wq only (32 MB) — xb eliminated with conv_kernel
    __hip_bfloat16* Wq = (__hip_bfloat16*)d_ws;

    // 1) dequant + LoRA fold (unchanged)
    deq_kernel<<<DEQ_BLOCKS, 256, 0, stream>>>(qw, scales, lA, lB, Wq);
    // 2) main GEMM in two M=4096 halves (grid 256 = 1 block/CU each);
    //    A converted fp32->bf16 inside the staging path.
    const size_t xhalf = (size_t)4096 * IN_F;       // fp32 elements
    const size_t ohalf = (size_t)4096 * OUT_F;      // fp32 elements
    qlora_gemm_kernel<<<dim3(256), dim3(512), 0, stream>>>(x, Wq, bias, out);
    qlora_gemm_kernel<<<dim3(256), dim3(512), 0, stream>>>(x + xhalf, Wq, bias, out + ohalf);
}